// Round 7
// baseline (138.270 us; speedup 1.0000x reference)
//
#include <hip/hip_runtime.h>
#include <hip/hip_bf16.h>
#include <hip/hip_fp16.h>

// GCN round 7: fp16 MFMA GEMMs (fp32 accum), fp16 h/hw tables, packed 4B CSR.
// Claim-based CSR build: hist(+prep fused) -> scan -> passB(re-hist, atomic
// claim, LDS-cursor scatter). No counts matrix, no mkbase kernel.

#define NNODES 10000
#define NEDGES 640000
#define HDIM   128
#define CDIM   64
#define NLAYER 3
#define NB_H   200            // hist blocks (blocks 5..204 of fused kernel)
#define CHUNK_H (NEDGES / NB_H)
#define NB_B   200            // passB blocks
#define CHUNK_B (NEDGES / NB_B)

typedef _Float16 half8 __attribute__((ext_vector_type(8)));
typedef float    f32x4 __attribute__((ext_vector_type(4)));

// ---------------- fused prep (5 blocks) + hist (200 blocks) ----------------
// total must be zeroed (hipMemsetAsync) before this kernel.
__global__ __launch_bounds__(256) void prep_hist_kernel(
    const float* __restrict__ enc_W,
    const float* __restrict__ conv_W,
    const float* __restrict__ dec_W,
    const int* __restrict__ dst,
    _Float16* __restrict__ wt_all,     // enc[16384] conv[3*16384] dec[8192]
    int* __restrict__ total)
{
    const int b = blockIdx.x, t = threadIdx.x;
    if (b < 5) {
        const float* W; _Float16* Wt; int NC, tot;
        if (b == 0)      { W = enc_W;                  Wt = wt_all;             NC = 128; tot = 16384; }
        else if (b <= 3) { W = conv_W + (b - 1) * 16384; Wt = wt_all + b * 16384; NC = 128; tot = 16384; }
        else             { W = dec_W;                  Wt = wt_all + 4 * 16384; NC = 64;  tot = 8192; }
        for (int idx = t; idx < tot; idx += 256) {
            int n = idx >> 7, k = idx & 127;
            Wt[idx] = (_Float16)W[k * NC + n];
        }
        return;
    }
    // hist role: per-block LDS histogram, flush nonzero to global total
    __shared__ int hist[NNODES];
    for (int i = t; i < NNODES; i += 256) hist[i] = 0;
    __syncthreads();
    const int hb = b - 5;
    const int e0 = hb * CHUNK_H, e1 = e0 + CHUNK_H;
    for (int e = e0 + t; e < e1; e += 256) atomicAdd(&hist[dst[e]], 1);
    __syncthreads();
    for (int i = t; i < NNODES; i += 256) {
        int c = hist[i];
        if (c) atomicAdd(&total[i], c);
    }
}

// ---------------- scan: rs = exclusive_scan(total); cur = rs ----------------
__global__ __launch_bounds__(1024) void scan_kernel(const int* __restrict__ total,
                                                    int* __restrict__ rs,
                                                    int* __restrict__ cur)
{
    __shared__ int part[1024];
    const int t = threadIdx.x;
    const int per = (NNODES + 1023) / 1024;
    const int begin = t * per;
    int s = 0;
    for (int j = 0; j < per; ++j) {
        int i = begin + j;
        if (i < NNODES) s += total[i];
    }
    part[t] = s;
    __syncthreads();
    for (int off = 1; off < 1024; off <<= 1) {
        int v = (t >= off) ? part[t - off] : 0;
        __syncthreads();
        part[t] += v;
        __syncthreads();
    }
    int excl = part[t] - s;
    for (int j = 0; j < per; ++j) {
        int i = begin + j;
        if (i < NNODES) {
            rs[i]  = excl;
            cur[i] = excl;
            excl += total[i];
        }
    }
    if (t == 1023) rs[NNODES] = part[1023];
}

// ---------------- passB: re-hist, atomic claim, LDS-cursor scatter ----------------
__global__ __launch_bounds__(1024) void passB_claim(const int* __restrict__ src,
                                                    const int* __restrict__ dst,
                                                    const float* __restrict__ ew,
                                                    int* __restrict__ cur,
                                                    unsigned int* __restrict__ csr)
{
    __shared__ int hist[NNODES];
    const int b = blockIdx.x, t = threadIdx.x;
    for (int i = t; i < NNODES; i += 1024) hist[i] = 0;
    __syncthreads();
    const int e0 = b * CHUNK_B, e1 = e0 + CHUNK_B;
    for (int e = e0 + t; e < e1; e += 1024) atomicAdd(&hist[dst[e]], 1);
    __syncthreads();
    // claim global slot ranges; store block-local base back into hist
    for (int i = t; i < NNODES; i += 1024) {
        int c = hist[i];
        if (c) hist[i] = atomicAdd(&cur[i], c);
    }
    __syncthreads();
    // scatter via LDS cursors
    for (int e = e0 + t; e < e1; e += 1024) {
        int d = dst[e];
        int p = atomicAdd(&hist[d], 1);
        unsigned int pk = (unsigned int)src[e]
                        | ((unsigned int)__half_as_ushort(__float2half_rn(ew[e])) << 16);
        csr[p] = pk;
    }
}

// ---------------- MFMA GEMM: out[M,NCOLS] = A[M,128] @ Wt^T (+bias)(+tanh) ----------------
template<int NCOLS, bool BIAS, bool TANH, bool OUTF32, bool AF32>
__global__ __launch_bounds__(256) void gemm_mfma(
    const void* __restrict__ Av,       // [M,128] fp32 or fp16 row-major
    const _Float16* __restrict__ Wt,   // [NCOLS,128] fp16 (n-major)
    const float* __restrict__ bias,    // [NCOLS] fp32
    void* __restrict__ outv,           // [M,NCOLS] fp16 or fp32
    int M)
{
    constexpr int TPW = NCOLS / 64;    // n-tiles per wave
    const int wave = __builtin_amdgcn_readfirstlane(threadIdx.x >> 6);
    const int lane = threadIdx.x & 63;
    const int base = blockIdx.x * 16;
    const int m  = lane & 15;
    const int kg = lane >> 4;
    const int row = base + m;

    f32x4 acc[TPW];
    #pragma unroll
    for (int t = 0; t < TPW; ++t) acc[t] = (f32x4){0.f, 0.f, 0.f, 0.f};

    #pragma unroll
    for (int ks = 0; ks < 4; ++ks) {
        half8 a;
        if (AF32) {
            const float* ap = (const float*)Av + (size_t)row * 128 + kg * 8 + ks * 32;
            float4 u0 = *(const float4*)(ap);
            float4 u1 = *(const float4*)(ap + 4);
            a[0] = (_Float16)u0.x; a[1] = (_Float16)u0.y;
            a[2] = (_Float16)u0.z; a[3] = (_Float16)u0.w;
            a[4] = (_Float16)u1.x; a[5] = (_Float16)u1.y;
            a[6] = (_Float16)u1.z; a[7] = (_Float16)u1.w;
        } else {
            a = *(const half8*)((const _Float16*)Av + (size_t)row * 128 + kg * 8 + ks * 32);
        }
        #pragma unroll
        for (int t = 0; t < TPW; ++t) {
            const int nt = wave + t * 4;
            half8 b = *(const half8*)(Wt + (size_t)(nt * 16 + m) * 128 + ks * 32 + kg * 8);
            acc[t] = __builtin_amdgcn_mfma_f32_16x16x32_f16(a, b, acc[t], 0, 0, 0);
        }
    }

    #pragma unroll
    for (int t = 0; t < TPW; ++t) {
        const int nt  = wave + t * 4;
        const int col = nt * 16 + m;
        float bv = BIAS ? bias[col] : 0.f;
        #pragma unroll
        for (int r = 0; r < 4; ++r) {
            int orow = base + kg * 4 + r;
            float v = acc[t][r] + bv;
            if (TANH) v = tanhf(v);
            if (OUTF32) ((float*)outv)[(size_t)orow * NCOLS + col] = v;
            else        ((_Float16*)outv)[(size_t)orow * NCOLS + col] = (_Float16)v;
        }
    }
}

// ---------------- pull aggregation: 1 wave/node, scalar packed edge stream ----------------
__global__ __launch_bounds__(256) void aggregate_kernel(
    const unsigned int* __restrict__ hwu,  // [N][64] fp16x2 rows
    const int* __restrict__ rs,            // [N+1]
    const unsigned int* __restrict__ csr,  // [E] packed (src | f16w<<16)
    const float* __restrict__ bias,        // [128] fp32
    unsigned int* __restrict__ hout,       // [N][64] fp16x2 rows
    int N)
{
    const int wv   = __builtin_amdgcn_readfirstlane(threadIdx.x >> 6);
    const int wid  = blockIdx.x * 4 + wv;
    const int lane = threadIdx.x & 63;
    if (wid >= N) return;

    const int e0 = rs[wid];
    const int e1 = rs[wid + 1];

    float ax = 0.f, ay = 0.f;
    int e = e0;
    for (; e + 16 <= e1; e += 16) {
        unsigned int p[16];
        #pragma unroll
        for (int j = 0; j < 16; ++j) p[j] = csr[e + j];          // uniform -> s_load
        unsigned int v[16];
        #pragma unroll
        for (int j = 0; j < 16; ++j) v[j] = hwu[((p[j] & 0x3FFFu) << 6) + lane];
        #pragma unroll
        for (int j = 0; j < 16; ++j) {
            __half wh; *(unsigned short*)&wh = (unsigned short)(p[j] >> 16);
            float w  = __half2float(wh);
            float2 f = __half22float2(*(const __half2*)&v[j]);
            ax += w * f.x;
            ay += w * f.y;
        }
    }
    for (; e + 4 <= e1; e += 4) {
        unsigned int p[4];
        #pragma unroll
        for (int j = 0; j < 4; ++j) p[j] = csr[e + j];
        unsigned int v[4];
        #pragma unroll
        for (int j = 0; j < 4; ++j) v[j] = hwu[((p[j] & 0x3FFFu) << 6) + lane];
        #pragma unroll
        for (int j = 0; j < 4; ++j) {
            __half wh; *(unsigned short*)&wh = (unsigned short)(p[j] >> 16);
            float w  = __half2float(wh);
            float2 f = __half22float2(*(const __half2*)&v[j]);
            ax += w * f.x;
            ay += w * f.y;
        }
    }
    for (; e < e1; ++e) {
        unsigned int p = csr[e];
        __half wh; *(unsigned short*)&wh = (unsigned short)(p >> 16);
        float w  = __half2float(wh);
        unsigned int u = hwu[((p & 0x3FFFu) << 6) + lane];
        float2 f = __half22float2(*(const __half2*)&u);
        ax += w * f.x;
        ay += w * f.y;
    }

    float2 bv = ((const float2*)bias)[lane];
    __half2 o = __floats2half2_rn(tanhf(ax + bv.x), tanhf(ay + bv.y));
    hout[((size_t)wid << 6) + lane] = *(unsigned int*)&o;
}

// ---------------- launch ----------------
extern "C" void kernel_launch(void* const* d_in, const int* in_sizes, int n_in,
                              void* d_out, int out_size, void* d_ws, size_t ws_size,
                              hipStream_t stream)
{
    const float* x      = (const float*)d_in[0];
    const int*   ei     = (const int*)  d_in[1];
    const float* ew     = (const float*)d_in[2];
    const float* enc_W  = (const float*)d_in[3];
    const float* enc_b  = (const float*)d_in[4];
    const float* conv_W = (const float*)d_in[5];
    const float* conv_b = (const float*)d_in[6];
    const float* dec_W  = (const float*)d_in[7];
    const float* dec_b  = (const float*)d_in[8];
    float* out = (float*)d_out;

    const int N = NNODES, E = NEDGES, H = HDIM;

    // workspace layout
    _Float16*     h      = (_Float16*)d_ws;                     // [N,128]  2.56MB
    _Float16*     hw     = h + (size_t)N * H;                   // [N,128]  2.56MB
    _Float16*     wt_all = hw + (size_t)N * H;                  // 81920    160KB
    unsigned int* csr    = (unsigned int*)(wt_all + 5 * 16384); // [E]      2.56MB
    int*          total  = (int*)(csr + E);                     // [N]
    int*          rs     = total + N;                           // [N+1]
    int*          cur    = rs + (N + 1);                        // [N]

    const int* src = ei;
    const int* dst = ei + E;

    hipMemsetAsync(total, 0, N * sizeof(int), stream);
    prep_hist_kernel<<<5 + NB_H, 256, 0, stream>>>(enc_W, conv_W, dec_W, dst, wt_all, total);

    // encoder (fp32 A converted in-register): h = tanh(x @ enc_W + enc_b)
    gemm_mfma<128, true, true, false, true><<<N / 16, 256, 0, stream>>>(x, wt_all, enc_b, h, N);

    scan_kernel<<<1, 1024, 0, stream>>>(total, rs, cur);
    passB_claim<<<NB_B, 1024, 0, stream>>>(src, dst, ew, cur, csr);

    for (int i = 0; i < NLAYER; ++i) {
        gemm_mfma<128, false, false, false, false><<<N / 16, 256, 0, stream>>>(h, wt_all + (1 + i) * 16384, nullptr, hw, N);
        aggregate_kernel<<<(N + 3) / 4, 256, 0, stream>>>((const unsigned int*)hw, rs, csr,
                                                          conv_b + (size_t)i * H, (unsigned int*)h, N);
    }

    // decoder: out = h @ dec_W + dec_b (fp32 out)
    gemm_mfma<64, true, false, true, false><<<N / 16, 256, 0, stream>>>(h, wt_all + 4 * 16384, dec_b, out, N);
}